// Round 5
// baseline (999.420 us; speedup 1.0000x reference)
//
#include <hip/hip_runtime.h>
#include <hip/hip_bf16.h>

#define B_    4
#define KL_   128
#define XL_   4096
#define DIM_  256
#define H_    8
#define HD_   32
#define PB_   8
#define NDIS_ 66
#define TDIM_ 768
#define SCALE_ 0.17677669529663687f

// ---- staged-buffer accessors (f32 or bf16 staging) -------------------------
__device__ __forceinline__ float lds_f(const float* p, size_t i) { return p[i]; }
__device__ __forceinline__ float lds_f(const __hip_bfloat16* p, size_t i) { return __bfloat162float(p[i]); }
__device__ __forceinline__ void sts_f(float* p, size_t i, float v) { p[i] = v; }
__device__ __forceinline__ void sts_f(__hip_bfloat16* p, size_t i, float v) { p[i] = __float2bfloat16(v); }

// ---------------------------------------------------------------------------
// GEMM: C[M,N] = A[M,K] @ B[K,N] (+ bias). A: f32 raw; B/bias: f32 raw;
// C: staged type (float or bf16) or final float out.
// ---------------------------------------------------------------------------
template <typename TC>
__global__ __launch_bounds__(256) void gemm_f32(const float* __restrict__ A,
                                                const float* __restrict__ Bw,
                                                TC* __restrict__ C,
                                                const float* __restrict__ bias,
                                                int M, int N, int K) {
    __shared__ __align__(16) float As[16][65];
    __shared__ __align__(16) float Bs[16][64];
    const int tid = threadIdx.x;
    const int tx = tid & 15, ty = tid >> 4;
    const int bn = blockIdx.x * 64, bm = blockIdx.y * 64;
    float acc[4][4] = {};
    for (int k0 = 0; k0 < K; k0 += 16) {
#pragma unroll
        for (int i = 0; i < 4; ++i) {
            int idx = tid + 256 * i;
            int m = idx >> 4, kk = idx & 15;
            As[kk][m] = A[(size_t)(bm + m) * K + k0 + kk];
        }
#pragma unroll
        for (int i = 0; i < 4; ++i) {
            int idx = tid + 256 * i;
            int kk = idx >> 6, n = idx & 63;
            Bs[kk][n] = Bw[(size_t)(k0 + kk) * N + bn + n];
        }
        __syncthreads();
#pragma unroll
        for (int kk = 0; kk < 16; ++kk) {
            float a[4], b[4];
#pragma unroll
            for (int i = 0; i < 4; ++i) a[i] = As[kk][ty * 4 + i];
#pragma unroll
            for (int j = 0; j < 4; ++j) b[j] = Bs[kk][tx * 4 + j];
#pragma unroll
            for (int i = 0; i < 4; ++i)
#pragma unroll
                for (int j = 0; j < 4; ++j) acc[i][j] += a[i] * b[j];
        }
        __syncthreads();
    }
#pragma unroll
    for (int i = 0; i < 4; ++i) {
        int m = bm + ty * 4 + i;
#pragma unroll
        for (int j = 0; j < 4; ++j) {
            int n = bn + tx * 4 + j;
            float v = acc[i][j];
            if (bias) v += bias[n];
            sts_f(C, (size_t)m * N + n, v);
        }
    }
}

// GEMM with staged A (float or bf16), f32 output + bias
template <typename TA>
__global__ __launch_bounds__(256) void gemm_staged(const TA* __restrict__ A,
                                                   const float* __restrict__ Bw,
                                                   float* __restrict__ C,
                                                   const float* __restrict__ bias,
                                                   int M, int N, int K) {
    __shared__ __align__(16) float As[16][65];
    __shared__ __align__(16) float Bs[16][64];
    const int tid = threadIdx.x;
    const int tx = tid & 15, ty = tid >> 4;
    const int bn = blockIdx.x * 64, bm = blockIdx.y * 64;
    float acc[4][4] = {};
    for (int k0 = 0; k0 < K; k0 += 16) {
#pragma unroll
        for (int i = 0; i < 4; ++i) {
            int idx = tid + 256 * i;
            int m = idx >> 4, kk = idx & 15;
            As[kk][m] = lds_f(A, (size_t)(bm + m) * K + k0 + kk);
        }
#pragma unroll
        for (int i = 0; i < 4; ++i) {
            int idx = tid + 256 * i;
            int kk = idx >> 6, n = idx & 63;
            Bs[kk][n] = Bw[(size_t)(k0 + kk) * N + bn + n];
        }
        __syncthreads();
#pragma unroll
        for (int kk = 0; kk < 16; ++kk) {
            float a[4], b[4];
#pragma unroll
            for (int i = 0; i < 4; ++i) a[i] = As[kk][ty * 4 + i];
#pragma unroll
            for (int j = 0; j < 4; ++j) b[j] = Bs[kk][tx * 4 + j];
#pragma unroll
            for (int i = 0; i < 4; ++i)
#pragma unroll
                for (int j = 0; j < 4; ++j) acc[i][j] += a[i] * b[j];
        }
        __syncthreads();
    }
#pragma unroll
    for (int i = 0; i < 4; ++i) {
        int m = bm + ty * 4 + i;
#pragma unroll
        for (int j = 0; j < 4; ++j) {
            int n = bn + tx * 4 + j;
            C[(size_t)m * N + n] = acc[i][j] + bias[n];
        }
    }
}

// ---------------------------------------------------------------------------
// Fused k-direction: per (b,h,k): scores over x (once, into LDS) ->
// polar-bin |.| sums -> argmax (main_ori, also stored for attn_x) ->
// mask/bias/softmax -> @ v -> kout_pre.
// ---------------------------------------------------------------------------
template <typename TS>
__global__ __launch_bounds__(256) void attn_k_ori(const float* __restrict__ qkv_k,
                                                  const TS* __restrict__ qkv_x,
                                                  const int* __restrict__ rd,
                                                  const int* __restrict__ polar_pos,
                                                  const int* __restrict__ att_mask,
                                                  const float* __restrict__ dis_embed,
                                                  const float* __restrict__ polar_emb,
                                                  int* __restrict__ main_ori,
                                                  float* __restrict__ kout_pre) {
    const int b = blockIdx.z, h = blockIdx.y, k = blockIdx.x;
    const int tid = threadIdx.x;
    __shared__ float tv[XL_];
    __shared__ float kq[HD_];
    __shared__ float de[NDIS_ * H_];
    __shared__ float pe[PB_];
    __shared__ float red[256];
    __shared__ float tot[PB_];
    __shared__ int mo_sh;
    __shared__ float outp[8][32];

    for (int i = tid; i < NDIS_ * H_; i += 256) de[i] = dis_embed[i];
    if (tid < PB_) pe[tid] = polar_emb[tid];
    if (tid < HD_) kq[tid] = qkv_k[(size_t)(b * KL_ + k) * TDIM_ + h * HD_ + tid];
    __syncthreads();

    const size_t prow = (size_t)(b * KL_ + k) * XL_;
    const size_t mbase = (size_t)(b * H_ + h) * XL_;

    // pass 1: raw scaled scores into LDS + polar-bin |.| partial sums
    float bins[PB_] = {};
    for (int x = tid; x < XL_; x += 256) {
        const TS* px = qkv_x + (size_t)(b * XL_ + x) * TDIM_ + DIM_ + h * HD_;
        float s = 0.f;
#pragma unroll
        for (int d = 0; d < HD_; ++d) s += kq[d] * lds_f(px, d);
        s *= SCALE_;
        tv[x] = s;
        int o = polar_pos[prow + x];
        float a = fabsf(s);
#pragma unroll
        for (int q = 0; q < PB_; ++q) bins[q] += (o == q) ? a : 0.0f;
    }
    // reduce bins, argmax
    for (int q = 0; q < PB_; ++q) {
        red[tid] = bins[q];
        __syncthreads();
        for (int st = 128; st > 0; st >>= 1) {
            if (tid < st) red[tid] += red[tid + st];
            __syncthreads();
        }
        if (tid == 0) tot[q] = red[0];
        __syncthreads();
    }
    if (tid == 0) {
        float best = tot[0];
        int bi = 0;
        for (int q = 1; q < PB_; ++q)
            if (tot[q] > best) { best = tot[q]; bi = q; }
        mo_sh = bi;
        main_ori[(b * H_ + h) * KL_ + k] = bi;
    }
    __syncthreads();
    const int mo = mo_sh;

    // pass 2: mask + biases, row max
    float lmax = -3e38f;
    for (int x = tid; x < XL_; x += 256) {
        float s = tv[x];
        int msk = att_mask[(mbase + x) * KL_ + k];
        int r = rd[prow + x];
        int pp = polar_pos[prow + x];
        int npb = pp - mo;
        npb += (npb >> 31) & PB_;
        float t = (msk ? -1e6f : s) + de[r * H_ + h] + pe[npb];
        tv[x] = t;
        lmax = fmaxf(lmax, t);
    }
    red[tid] = lmax;
    __syncthreads();
    for (int st = 128; st > 0; st >>= 1) {
        if (tid < st) red[tid] = fmaxf(red[tid], red[tid + st]);
        __syncthreads();
    }
    const float gmax = red[0];
    __syncthreads();

    float lsum = 0.f;
    for (int x = tid; x < XL_; x += 256) {
        float e = expf(tv[x] - gmax);
        tv[x] = e;
        lsum += e;
    }
    red[tid] = lsum;
    __syncthreads();
    for (int st = 128; st > 0; st >>= 1) {
        if (tid < st) red[tid] += red[tid + st];
        __syncthreads();
    }
    const float gsum = red[0];
    __syncthreads();

    // @ v
    const int d = tid & 31, c = tid >> 5;
    const TS* vp = qkv_x + (size_t)(b * XL_ + c * 512) * TDIM_ + 2 * DIM_ + h * HD_ + d;
    float acc = 0.f;
    int xb = c * 512;
#pragma unroll 4
    for (int i = 0; i < 512; ++i) {
        acc += tv[xb + i] * lds_f(vp, 0);
        vp += TDIM_;
    }
    outp[c][d] = acc;
    __syncthreads();
    if (tid < 32) {
        float o = 0.f;
#pragma unroll
        for (int cc = 0; cc < 8; ++cc) o += outp[cc][tid];
        kout_pre[(size_t)(b * KL_ + k) * DIM_ + h * HD_ + tid] = o / gsum;
    }
}

// ---------------------------------------------------------------------------
// x-direction attention: block = (b,h,16 x-positions); scores over kl=128
// ---------------------------------------------------------------------------
template <typename TS>
__global__ __launch_bounds__(256) void attn_x(const TS* __restrict__ qkv_x,
                                              const float* __restrict__ qkv_k,
                                              const int* __restrict__ rd,
                                              const int* __restrict__ polar_pos,
                                              const int* __restrict__ att_mask,
                                              const float* __restrict__ dis_embed,
                                              const float* __restrict__ polar_emb,
                                              const int* __restrict__ main_ori,
                                              TS* __restrict__ xout_pre) {
    const int b = blockIdx.z, h = blockIdx.y;
    const int x0 = blockIdx.x * 16;
    const int tid = threadIdx.x;
    __shared__ __align__(16) float kk_s[KL_][36];
    __shared__ __align__(16) float kv_s[KL_][36];
    __shared__ __align__(16) float q_s[16][36];
    __shared__ float de[NDIS_ * H_];
    __shared__ float pe[PB_];
    __shared__ int mo_s[KL_];

    for (int i = tid; i < KL_ * HD_; i += 256) {
        int kk = i >> 5, d = i & 31;
        size_t base = (size_t)(b * KL_ + kk) * TDIM_ + h * HD_ + d;
        kk_s[kk][d] = qkv_k[base + DIM_];
        kv_s[kk][d] = qkv_k[base + 2 * DIM_];
    }
    for (int i = tid; i < 16 * HD_; i += 256) {
        int xl = i >> 5, d = i & 31;
        q_s[xl][d] = lds_f(qkv_x, (size_t)(b * XL_ + x0 + xl) * TDIM_ + h * HD_ + d);
    }
    for (int i = tid; i < NDIS_ * H_; i += 256) de[i] = dis_embed[i];
    if (tid < PB_) pe[tid] = polar_emb[tid];
    if (tid < KL_) mo_s[tid] = main_ori[(b * H_ + h) * KL_ + tid];
    __syncthreads();

    const int xl = tid >> 4, r = tid & 15;
    const int x = x0 + xl;
    float t[8];
    float lmax = -3e38f;
    const size_t mrow = ((size_t)(b * H_ + h) * XL_ + x) * KL_;
#pragma unroll
    for (int j = 0; j < 8; ++j) {
        int kk = j * 16 + r;
        float s = 0.f;
#pragma unroll
        for (int d4 = 0; d4 < 8; ++d4) {
            float4 a = *(const float4*)&q_s[xl][d4 * 4];
            float4 bb = *(const float4*)&kk_s[kk][d4 * 4];
            s += a.x * bb.x + a.y * bb.y + a.z * bb.z + a.w * bb.w;
        }
        s *= SCALE_;
        int msk = att_mask[mrow + kk];
        size_t pidx = (size_t)(b * KL_ + kk) * XL_ + x;
        int rv = rd[pidx];
        int pp = polar_pos[pidx];
        int npb = pp - mo_s[kk];
        npb += (npb >> 31) & PB_;
        t[j] = (msk ? -1e9f : s) + de[rv * H_ + h] + pe[npb];
        lmax = fmaxf(lmax, t[j]);
    }
#pragma unroll
    for (int m = 1; m < 16; m <<= 1) lmax = fmaxf(lmax, __shfl_xor(lmax, m, 16));
    float lsum = 0.f;
#pragma unroll
    for (int j = 0; j < 8; ++j) {
        t[j] = expf(t[j] - lmax);
        lsum += t[j];
    }
#pragma unroll
    for (int m = 1; m < 16; m <<= 1) lsum += __shfl_xor(lsum, m, 16);

    float acc[HD_] = {};
#pragma unroll
    for (int j = 0; j < 8; ++j) {
        int kk = j * 16 + r;
        float e = t[j];
#pragma unroll
        for (int d = 0; d < HD_; d += 4) {
            float4 vv = *(const float4*)&kv_s[kk][d];
            acc[d + 0] += e * vv.x;
            acc[d + 1] += e * vv.y;
            acc[d + 2] += e * vv.z;
            acc[d + 3] += e * vv.w;
        }
    }
#pragma unroll
    for (int d = 0; d < HD_; ++d)
#pragma unroll
        for (int m = 1; m < 16; m <<= 1) acc[d] += __shfl_xor(acc[d], m, 16);
    if (r == 0) {
        float inv = 1.0f / lsum;
        size_t obase = (size_t)(b * XL_ + x) * DIM_ + h * HD_;
#pragma unroll
        for (int d = 0; d < HD_; ++d) sts_f(xout_pre, obase + d, acc[d] * inv);
    }
}

// ---------------------------------------------------------------------------
template <typename TS>
static void run_pipeline(const float* x, const float* kernal, const int* rd,
                         const int* polar_pos, const int* att_mask,
                         const float* W_qkv, const float* dis_embed, const float* polar_emb,
                         const float* W_proj, const float* b_proj,
                         float* out, char* base, hipStream_t stream) {
    size_t off = 0;
    auto alloc = [&](size_t bytes) { void* p = base + off; off = (off + bytes + 255) & ~255ULL; return p; };
    TS* qkv_x       = (TS*)alloc((size_t)B_ * XL_ * TDIM_ * sizeof(TS));
    float* qkv_k    = (float*)alloc((size_t)B_ * KL_ * TDIM_ * 4);
    TS* xout_pre    = (TS*)alloc((size_t)B_ * XL_ * DIM_ * sizeof(TS));
    float* kout_pre = (float*)alloc((size_t)B_ * KL_ * DIM_ * 4);
    int* main_ori   = (int*)alloc(B_ * H_ * KL_ * 4);

    gemm_f32<TS><<<dim3(TDIM_ / 64, (B_ * XL_) / 64), 256, 0, stream>>>(
        x, W_qkv, qkv_x, nullptr, B_ * XL_, TDIM_, DIM_);
    gemm_f32<float><<<dim3(TDIM_ / 64, (B_ * KL_) / 64), 256, 0, stream>>>(
        kernal, W_qkv, qkv_k, nullptr, B_ * KL_, TDIM_, DIM_);
    attn_k_ori<TS><<<dim3(KL_, H_, B_), 256, 0, stream>>>(
        qkv_k, qkv_x, rd, polar_pos, att_mask, dis_embed, polar_emb, main_ori, kout_pre);
    attn_x<TS><<<dim3(XL_ / 16, H_, B_), 256, 0, stream>>>(
        qkv_x, qkv_k, rd, polar_pos, att_mask, dis_embed, polar_emb, main_ori, xout_pre);
    gemm_staged<TS><<<dim3(DIM_ / 64, (B_ * XL_) / 64), 256, 0, stream>>>(
        xout_pre, W_proj, out, b_proj, B_ * XL_, DIM_, DIM_);
    gemm_staged<float><<<dim3(DIM_ / 64, (B_ * KL_) / 64), 256, 0, stream>>>(
        kout_pre, W_proj, out + (size_t)B_ * XL_ * DIM_, b_proj, B_ * KL_, DIM_, DIM_);
}

extern "C" void kernel_launch(void* const* d_in, const int* in_sizes, int n_in,
                              void* d_out, int out_size, void* d_ws, size_t ws_size,
                              hipStream_t stream) {
    const float* x         = (const float*)d_in[0];
    const float* kernal    = (const float*)d_in[1];
    const int* rd          = (const int*)d_in[2];
    const int* polar_pos   = (const int*)d_in[3];
    const int* att_mask    = (const int*)d_in[4];
    const float* W_qkv     = (const float*)d_in[5];
    const float* dis_embed = (const float*)d_in[6];
    const float* polar_emb = (const float*)d_in[7];
    const float* W_proj    = (const float*)d_in[8];
    const float* b_proj    = (const float*)d_in[9];
    float* out             = (float*)d_out;   // reference output dtype = float32

    // f32 staging needs ~69.3 MB; bf16 staging ~35.7 MB fallback.
    const size_t NEED_F32 = ((size_t)B_ * XL_ * TDIM_ + (size_t)B_ * KL_ * TDIM_ +
                             (size_t)B_ * XL_ * DIM_ + (size_t)B_ * KL_ * DIM_) * 4
                            + B_ * H_ * KL_ * 4 + 4096;
    if (ws_size >= NEED_F32)
        run_pipeline<float>(x, kernal, rd, polar_pos, att_mask, W_qkv, dis_embed,
                            polar_emb, W_proj, b_proj, out, (char*)d_ws, stream);
    else
        run_pipeline<__hip_bfloat16>(x, kernal, rd, polar_pos, att_mask, W_qkv, dis_embed,
                                     polar_emb, W_proj, b_proj, out, (char*)d_ws, stream);
}

// Round 6
// 628.947 us; speedup vs baseline: 1.5890x; 1.5890x over previous
//
#include <hip/hip_runtime.h>
#include <hip/hip_bf16.h>

#define B_    4
#define KL_   128
#define XL_   4096
#define DIM_  256
#define H_    8
#define HD_   32
#define PB_   8
#define NDIS_ 66
#define TDIM_ 768
#define SCALE_ 0.17677669529663687f
#define XT_   64   // x tile for flash kernel
#define KC_   8    // k rows per block

// ---------------------------------------------------------------------------
// GEMM: C[M,N] = A[M,K] @ B[K,N] (+ bias). 64x64 tile, BK=16, float4 LDS.
// ---------------------------------------------------------------------------
__global__ __launch_bounds__(256) void gemm64(const float* __restrict__ A,
                                              const float* __restrict__ Bw,
                                              float* __restrict__ C,
                                              const float* __restrict__ bias,
                                              int M, int N, int K) {
    __shared__ __align__(16) float As[16][68];
    __shared__ __align__(16) float Bs[16][64];
    const int tid = threadIdx.x;
    const int tx = tid & 15, ty = tid >> 4;
    const int bn = blockIdx.x * 64, bm = blockIdx.y * 64;
    const int am = tid >> 2, ac = tid & 3;
    float acc[4][4] = {};
    for (int k0 = 0; k0 < K; k0 += 16) {
        float4 a4 = *(const float4*)&A[(size_t)(bm + am) * K + k0 + ac * 4];
        As[ac * 4 + 0][am] = a4.x;
        As[ac * 4 + 1][am] = a4.y;
        As[ac * 4 + 2][am] = a4.z;
        As[ac * 4 + 3][am] = a4.w;
        *(float4*)&Bs[ty][tx * 4] = *(const float4*)&Bw[(size_t)(k0 + ty) * N + bn + tx * 4];
        __syncthreads();
#pragma unroll
        for (int kk = 0; kk < 16; ++kk) {
            float4 av = *(const float4*)&As[kk][ty * 4];
            float4 bv = *(const float4*)&Bs[kk][tx * 4];
            float a[4] = {av.x, av.y, av.z, av.w};
            float b[4] = {bv.x, bv.y, bv.z, bv.w};
#pragma unroll
            for (int i = 0; i < 4; ++i)
#pragma unroll
                for (int j = 0; j < 4; ++j) acc[i][j] += a[i] * b[j];
        }
        __syncthreads();
    }
#pragma unroll
    for (int i = 0; i < 4; ++i) {
        int m = bm + ty * 4 + i;
#pragma unroll
        for (int j = 0; j < 4; ++j) {
            int n = bn + tx * 4 + j;
            float v = acc[i][j];
            if (bias) v += bias[n];
            C[(size_t)m * N + n] = v;
        }
    }
}

// ---------------------------------------------------------------------------
// Fused k-direction flash kernel. Block = (b, h, 8 k-rows); 256 thr =
// 8 ki x 32 xt. Pass A: scores -> polar bins -> argmax (block-local mo).
// Pass B: scores + bias -> online softmax -> @ v. Tiles staged in LDS.
// ---------------------------------------------------------------------------
__global__ __launch_bounds__(256) void attn_k_flash(const float* __restrict__ qkv_k,
                                                    const float* __restrict__ qkv_x,
                                                    const int* __restrict__ rd,
                                                    const int* __restrict__ polar_pos,
                                                    const int* __restrict__ att_mask,
                                                    const float* __restrict__ dis_embed,
                                                    const float* __restrict__ polar_emb,
                                                    int* __restrict__ main_ori,
                                                    float* __restrict__ kout_pre) {
    const int b = blockIdx.z, h = blockIdx.y, k0 = blockIdx.x * KC_;
    const int tid = threadIdx.x;
    const int ki = tid >> 5, xt = tid & 31;

    __shared__ __align__(16) float4 xs[XT_][9];     // keys tile
    __shared__ __align__(16) float4 vs[XT_][9];     // v tile
    __shared__ __align__(16) float kq_s[KC_][32];
    __shared__ int pol_s[KC_][68];
    __shared__ int rd_s[KC_][68];
    __shared__ int msk_s[KC_][65];
    __shared__ float de[NDIS_ * H_];
    __shared__ float pe[PB_];
    __shared__ int mo_s[KC_];

    for (int i = tid; i < NDIS_ * H_; i += 256) de[i] = dis_embed[i];
    if (tid < PB_) pe[tid] = polar_emb[tid];
    if (tid < KC_ * 8) {
        int kk = tid >> 3, c = tid & 7;
        *(float4*)&kq_s[kk][c * 4] =
            *(const float4*)&qkv_k[(size_t)(b * KL_ + k0 + kk) * TDIM_ + h * HD_ + c * 4];
    }
    __syncthreads();

    // own k_q row in registers
    float4 kqr[8];
#pragma unroll
    for (int c = 0; c < 8; ++c) kqr[c] = *(const float4*)&kq_s[ki][c * 4];

    const size_t xbase = (size_t)b * XL_;
    const size_t mrow_base = (size_t)(b * H_ + h) * XL_;

    // ---------------- pass A: polar bins -> argmax ----------------
    float bins[PB_] = {};
    for (int t = 0; t < XL_ / XT_; ++t) {
        const int x0 = t * XT_;
        __syncthreads();
#pragma unroll
        for (int i = 0; i < 2; ++i) {
            int id = tid + 256 * i;
            int row = id >> 3, c = id & 7;
            xs[row][c] = *(const float4*)&qkv_x[(xbase + x0 + row) * TDIM_ + DIM_ + h * HD_ + c * 4];
        }
        if (tid < 128) {
            int kk = tid >> 4, c = tid & 15;
            *(int4*)&pol_s[kk][c * 4] =
                *(const int4*)&polar_pos[(size_t)(b * KL_ + k0 + kk) * XL_ + x0 + c * 4];
        }
        __syncthreads();
#pragma unroll
        for (int j = 0; j < 2; ++j) {
            int x = xt + 32 * j;
            float s = 0.f;
#pragma unroll
            for (int c = 0; c < 8; ++c) {
                float4 kv = xs[x][c];
                s += kqr[c].x * kv.x + kqr[c].y * kv.y + kqr[c].z * kv.z + kqr[c].w * kv.w;
            }
            float a = fabsf(s * SCALE_);
            int o = pol_s[ki][x];
#pragma unroll
            for (int q = 0; q < PB_; ++q) bins[q] += (o == q) ? a : 0.0f;
        }
    }
#pragma unroll
    for (int q = 0; q < PB_; ++q)
#pragma unroll
        for (int m = 1; m < 32; m <<= 1) bins[q] += __shfl_xor(bins[q], m, 32);
    if (xt == 0) {
        float best = bins[0];
        int bi = 0;
#pragma unroll
        for (int q = 1; q < PB_; ++q)
            if (bins[q] > best) { best = bins[q]; bi = q; }
        mo_s[ki] = bi;
        main_ori[(b * H_ + h) * KL_ + k0 + ki] = bi;
    }
    __syncthreads();
    const int mo = mo_s[ki];

    // ---------------- pass B: online softmax + AV ----------------
    float m_run = -3e38f, l_run = 0.f;
    float4 acc[8] = {};
    for (int t = 0; t < XL_ / XT_; ++t) {
        const int x0 = t * XT_;
        __syncthreads();
#pragma unroll
        for (int i = 0; i < 2; ++i) {
            int id = tid + 256 * i;
            int row = id >> 3, c = id & 7;
            size_t rb = (xbase + x0 + row) * TDIM_ + h * HD_ + c * 4;
            xs[row][c] = *(const float4*)&qkv_x[rb + DIM_];
            vs[row][c] = *(const float4*)&qkv_x[rb + 2 * DIM_];
        }
        if (tid < 128) {
            int kk = tid >> 4, c = tid & 15;
            size_t rb = (size_t)(b * KL_ + k0 + kk) * XL_ + x0 + c * 4;
            *(int4*)&pol_s[kk][c * 4] = *(const int4*)&polar_pos[rb];
            *(int4*)&rd_s[kk][c * 4] = *(const int4*)&rd[rb];
        } else {
            int id = tid - 128;
            int row = id >> 1, half = id & 1;
            int4 m4 = *(const int4*)&att_mask[(mrow_base + x0 + row) * KL_ + k0 + half * 4];
            msk_s[half * 4 + 0][row] = m4.x;
            msk_s[half * 4 + 1][row] = m4.y;
            msk_s[half * 4 + 2][row] = m4.z;
            msk_s[half * 4 + 3][row] = m4.w;
        }
        __syncthreads();
#pragma unroll
        for (int j = 0; j < 2; ++j) {
            int x = xt + 32 * j;
            float s = 0.f;
#pragma unroll
            for (int c = 0; c < 8; ++c) {
                float4 kv = xs[x][c];
                s += kqr[c].x * kv.x + kqr[c].y * kv.y + kqr[c].z * kv.z + kqr[c].w * kv.w;
            }
            s *= SCALE_;
            int r = rd_s[ki][x];
            int pp = pol_s[ki][x];
            int npb = pp - mo;
            npb += (npb >> 31) & PB_;
            float tval = (msk_s[ki][x] ? -1e6f : s) + de[r * H_ + h] + pe[npb];
            if (tval > m_run) {
                float alpha = expf(m_run - tval);
                l_run = l_run * alpha + 1.0f;
#pragma unroll
                for (int c = 0; c < 8; ++c) {
                    float4 vv = vs[x][c];
                    acc[c].x = acc[c].x * alpha + vv.x;
                    acc[c].y = acc[c].y * alpha + vv.y;
                    acc[c].z = acc[c].z * alpha + vv.z;
                    acc[c].w = acc[c].w * alpha + vv.w;
                }
                m_run = tval;
            } else {
                float p = expf(tval - m_run);
                l_run += p;
#pragma unroll
                for (int c = 0; c < 8; ++c) {
                    float4 vv = vs[x][c];
                    acc[c].x += p * vv.x;
                    acc[c].y += p * vv.y;
                    acc[c].z += p * vv.z;
                    acc[c].w += p * vv.w;
                }
            }
        }
    }
    // merge the 32 x-lane partials per k row
    float M = m_run;
#pragma unroll
    for (int m = 1; m < 32; m <<= 1) M = fmaxf(M, __shfl_xor(M, m, 32));
    float factor = expf(m_run - M);
    l_run *= factor;
#pragma unroll
    for (int c = 0; c < 8; ++c) {
        acc[c].x *= factor; acc[c].y *= factor; acc[c].z *= factor; acc[c].w *= factor;
    }
#pragma unroll
    for (int m = 1; m < 32; m <<= 1) {
        l_run += __shfl_xor(l_run, m, 32);
#pragma unroll
        for (int c = 0; c < 8; ++c) {
            acc[c].x += __shfl_xor(acc[c].x, m, 32);
            acc[c].y += __shfl_xor(acc[c].y, m, 32);
            acc[c].z += __shfl_xor(acc[c].z, m, 32);
            acc[c].w += __shfl_xor(acc[c].w, m, 32);
        }
    }
    if (xt == 0) {
        float inv = 1.0f / l_run;
        float* op = kout_pre + (size_t)(b * KL_ + k0 + ki) * DIM_ + h * HD_;
#pragma unroll
        for (int c = 0; c < 8; ++c) {
            float4 o = acc[c];
            o.x *= inv; o.y *= inv; o.z *= inv; o.w *= inv;
            *(float4*)&op[c * 4] = o;
        }
    }
}

// ---------------------------------------------------------------------------
// x-direction attention: block = (b,h,16 x-positions); scores over kl=128
// ---------------------------------------------------------------------------
__global__ __launch_bounds__(256) void attn_x(const float* __restrict__ qkv_x,
                                              const float* __restrict__ qkv_k,
                                              const int* __restrict__ rd,
                                              const int* __restrict__ polar_pos,
                                              const int* __restrict__ att_mask,
                                              const float* __restrict__ dis_embed,
                                              const float* __restrict__ polar_emb,
                                              const int* __restrict__ main_ori,
                                              float* __restrict__ xout_pre) {
    const int b = blockIdx.z, h = blockIdx.y;
    const int x0 = blockIdx.x * 16;
    const int tid = threadIdx.x;
    __shared__ __align__(16) float kk_s[KL_][36];
    __shared__ __align__(16) float kv_s[KL_][36];
    __shared__ __align__(16) float q_s[16][36];
    __shared__ float de[NDIS_ * H_];
    __shared__ float pe[PB_];
    __shared__ int mo_s[KL_];

    for (int i = tid; i < KL_ * HD_; i += 256) {
        int kk = i >> 5, d = i & 31;
        size_t base = (size_t)(b * KL_ + kk) * TDIM_ + h * HD_ + d;
        kk_s[kk][d] = qkv_k[base + DIM_];
        kv_s[kk][d] = qkv_k[base + 2 * DIM_];
    }
    for (int i = tid; i < 16 * HD_; i += 256) {
        int xl = i >> 5, d = i & 31;
        q_s[xl][d] = qkv_x[(size_t)(b * XL_ + x0 + xl) * TDIM_ + h * HD_ + d];
    }
    for (int i = tid; i < NDIS_ * H_; i += 256) de[i] = dis_embed[i];
    if (tid < PB_) pe[tid] = polar_emb[tid];
    if (tid < KL_) mo_s[tid] = main_ori[(b * H_ + h) * KL_ + tid];
    __syncthreads();

    const int xl = tid >> 4, r = tid & 15;
    const int x = x0 + xl;
    float t[8];
    float lmax = -3e38f;
    const size_t mrow = ((size_t)(b * H_ + h) * XL_ + x) * KL_;
#pragma unroll
    for (int j = 0; j < 8; ++j) {
        int kk = j * 16 + r;
        float s = 0.f;
#pragma unroll
        for (int d4 = 0; d4 < 8; ++d4) {
            float4 a = *(const float4*)&q_s[xl][d4 * 4];
            float4 bb = *(const float4*)&kk_s[kk][d4 * 4];
            s += a.x * bb.x + a.y * bb.y + a.z * bb.z + a.w * bb.w;
        }
        s *= SCALE_;
        int msk = att_mask[mrow + kk];
        size_t pidx = (size_t)(b * KL_ + kk) * XL_ + x;
        int rv = rd[pidx];
        int pp = polar_pos[pidx];
        int npb = pp - mo_s[kk];
        npb += (npb >> 31) & PB_;
        t[j] = (msk ? -1e9f : s) + de[rv * H_ + h] + pe[npb];
        lmax = fmaxf(lmax, t[j]);
    }
#pragma unroll
    for (int m = 1; m < 16; m <<= 1) lmax = fmaxf(lmax, __shfl_xor(lmax, m, 16));
    float lsum = 0.f;
#pragma unroll
    for (int j = 0; j < 8; ++j) {
        t[j] = expf(t[j] - lmax);
        lsum += t[j];
    }
#pragma unroll
    for (int m = 1; m < 16; m <<= 1) lsum += __shfl_xor(lsum, m, 16);

    float acc[HD_] = {};
#pragma unroll
    for (int j = 0; j < 8; ++j) {
        int kk = j * 16 + r;
        float e = t[j];
#pragma unroll
        for (int d = 0; d < HD_; d += 4) {
            float4 vv = *(const float4*)&kv_s[kk][d];
            acc[d + 0] += e * vv.x;
            acc[d + 1] += e * vv.y;
            acc[d + 2] += e * vv.z;
            acc[d + 3] += e * vv.w;
        }
    }
#pragma unroll
    for (int d = 0; d < HD_; ++d)
#pragma unroll
        for (int m = 1; m < 16; m <<= 1) acc[d] += __shfl_xor(acc[d], m, 16);
    if (r == 0) {
        float inv = 1.0f / lsum;
        float* op = xout_pre + (size_t)(b * XL_ + x) * DIM_ + h * HD_;
#pragma unroll
        for (int d = 0; d < HD_; ++d) op[d] = acc[d] * inv;
    }
}

// ---------------------------------------------------------------------------
extern "C" void kernel_launch(void* const* d_in, const int* in_sizes, int n_in,
                              void* d_out, int out_size, void* d_ws, size_t ws_size,
                              hipStream_t stream) {
    const float* x         = (const float*)d_in[0];
    const float* kernal    = (const float*)d_in[1];
    const int* rd          = (const int*)d_in[2];
    const int* polar_pos   = (const int*)d_in[3];
    const int* att_mask    = (const int*)d_in[4];
    const float* W_qkv     = (const float*)d_in[5];
    const float* dis_embed = (const float*)d_in[6];
    const float* polar_emb = (const float*)d_in[7];
    const float* W_proj    = (const float*)d_in[8];
    const float* b_proj    = (const float*)d_in[9];
    float* out             = (float*)d_out;

    char* base = (char*)d_ws;
    size_t off = 0;
    auto alloc = [&](size_t bytes) { void* p = base + off; off = (off + bytes + 255) & ~255ULL; return p; };
    float* qkv_x    = (float*)alloc((size_t)B_ * XL_ * TDIM_ * 4);
    float* qkv_k    = (float*)alloc((size_t)B_ * KL_ * TDIM_ * 4);
    float* xout_pre = (float*)alloc((size_t)B_ * XL_ * DIM_ * 4);
    float* kout_pre = (float*)alloc((size_t)B_ * KL_ * DIM_ * 4);
    int* main_ori   = (int*)alloc(B_ * H_ * KL_ * 4);

    gemm64<<<dim3(TDIM_ / 64, (B_ * XL_) / 64), 256, 0, stream>>>(
        x, W_qkv, qkv_x, nullptr, B_ * XL_, TDIM_, DIM_);
    gemm64<<<dim3(TDIM_ / 64, (B_ * KL_) / 64), 256, 0, stream>>>(
        kernal, W_qkv, qkv_k, nullptr, B_ * KL_, TDIM_, DIM_);
    attn_k_flash<<<dim3(KL_ / KC_, H_, B_), 256, 0, stream>>>(
        qkv_k, qkv_x, rd, polar_pos, att_mask, dis_embed, polar_emb, main_ori, kout_pre);
    attn_x<<<dim3(XL_ / 16, H_, B_), 256, 0, stream>>>(
        qkv_x, qkv_k, rd, polar_pos, att_mask, dis_embed, polar_emb, main_ori, xout_pre);
    gemm64<<<dim3(DIM_ / 64, (B_ * XL_) / 64), 256, 0, stream>>>(
        xout_pre, W_proj, out, b_proj, B_ * XL_, DIM_, DIM_);
    gemm64<<<dim3(DIM_ / 64, (B_ * KL_) / 64), 256, 0, stream>>>(
        kout_pre, W_proj, out + (size_t)B_ * XL_ * DIM_, b_proj, B_ * KL_, DIM_, DIM_);
}

// Round 7
// 591.477 us; speedup vs baseline: 1.6897x; 1.0633x over previous
//
#include <hip/hip_runtime.h>
#include <hip/hip_bf16.h>

#define B_    4
#define KL_   128
#define XL_   4096
#define DIM_  256
#define H_    8
#define HD_   32
#define PB_   8
#define NDIS_ 66
#define TDIM_ 768
#define SCALE_ 0.17677669529663687f
#define XT_   64
#define KC_   8
#define NS_   4            // x-split chunks
#define XCH_  (XL_ / NS_)  // 1024

// ---------------------------------------------------------------------------
// 128x128 f32 GEMM, BK=8, 8x8 per thread. M%128==0, N%128==0, K%8==0.
// ---------------------------------------------------------------------------
__global__ __launch_bounds__(256) void gemm128(const float* __restrict__ A,
                                               const float* __restrict__ Bw,
                                               float* __restrict__ C,
                                               const float* __restrict__ bias,
                                               int M, int N, int K) {
    __shared__ __align__(16) float As[8][132];
    __shared__ __align__(16) float Bs[8][128];
    const int tid = threadIdx.x;
    const int tx = tid & 15, ty = tid >> 4;
    const int bn = blockIdx.x * 128, bm = blockIdx.y * 128;
    const int arow = tid >> 1, acol = (tid & 1) * 4;
    const int brow = tid >> 5, bcol = (tid & 31) * 4;
    float acc[8][8] = {};
    for (int k0 = 0; k0 < K; k0 += 8) {
        float4 a4 = *(const float4*)&A[(size_t)(bm + arow) * K + k0 + acol];
        As[acol + 0][arow] = a4.x;
        As[acol + 1][arow] = a4.y;
        As[acol + 2][arow] = a4.z;
        As[acol + 3][arow] = a4.w;
        *(float4*)&Bs[brow][bcol] = *(const float4*)&Bw[(size_t)(k0 + brow) * N + bn + bcol];
        __syncthreads();
#pragma unroll
        for (int kk = 0; kk < 8; ++kk) {
            float4 a0 = *(const float4*)&As[kk][ty * 8];
            float4 a1 = *(const float4*)&As[kk][ty * 8 + 4];
            float4 b0 = *(const float4*)&Bs[kk][tx * 8];
            float4 b1 = *(const float4*)&Bs[kk][tx * 8 + 4];
            float a[8] = {a0.x, a0.y, a0.z, a0.w, a1.x, a1.y, a1.z, a1.w};
            float b[8] = {b0.x, b0.y, b0.z, b0.w, b1.x, b1.y, b1.z, b1.w};
#pragma unroll
            for (int i = 0; i < 8; ++i)
#pragma unroll
                for (int j = 0; j < 8; ++j) acc[i][j] += a[i] * b[j];
        }
        __syncthreads();
    }
#pragma unroll
    for (int i = 0; i < 8; ++i) {
        int m = bm + ty * 8 + i;
        float* cp = &C[(size_t)m * N + bn + tx * 8];
        float4 o0 = {acc[i][0], acc[i][1], acc[i][2], acc[i][3]};
        float4 o1 = {acc[i][4], acc[i][5], acc[i][6], acc[i][7]};
        if (bias) {
            const float* bp = &bias[bn + tx * 8];
            o0.x += bp[0]; o0.y += bp[1]; o0.z += bp[2]; o0.w += bp[3];
            o1.x += bp[4]; o1.y += bp[5]; o1.z += bp[6]; o1.w += bp[7];
        }
        *(float4*)cp = o0;
        *(float4*)(cp + 4) = o1;
    }
}

// ---------------------------------------------------------------------------
// 64x64 f32 GEMM (for small-M GEMMs)
// ---------------------------------------------------------------------------
__global__ __launch_bounds__(256) void gemm64(const float* __restrict__ A,
                                              const float* __restrict__ Bw,
                                              float* __restrict__ C,
                                              const float* __restrict__ bias,
                                              int M, int N, int K) {
    __shared__ __align__(16) float As[16][68];
    __shared__ __align__(16) float Bs[16][64];
    const int tid = threadIdx.x;
    const int tx = tid & 15, ty = tid >> 4;
    const int bn = blockIdx.x * 64, bm = blockIdx.y * 64;
    const int am = tid >> 2, ac = tid & 3;
    float acc[4][4] = {};
    for (int k0 = 0; k0 < K; k0 += 16) {
        float4 a4 = *(const float4*)&A[(size_t)(bm + am) * K + k0 + ac * 4];
        As[ac * 4 + 0][am] = a4.x;
        As[ac * 4 + 1][am] = a4.y;
        As[ac * 4 + 2][am] = a4.z;
        As[ac * 4 + 3][am] = a4.w;
        *(float4*)&Bs[ty][tx * 4] = *(const float4*)&Bw[(size_t)(k0 + ty) * N + bn + tx * 4];
        __syncthreads();
#pragma unroll
        for (int kk = 0; kk < 16; ++kk) {
            float4 av = *(const float4*)&As[kk][ty * 4];
            float4 bv = *(const float4*)&Bs[kk][tx * 4];
            float a[4] = {av.x, av.y, av.z, av.w};
            float b[4] = {bv.x, bv.y, bv.z, bv.w};
#pragma unroll
            for (int i = 0; i < 4; ++i)
#pragma unroll
                for (int j = 0; j < 4; ++j) acc[i][j] += a[i] * b[j];
        }
        __syncthreads();
    }
#pragma unroll
    for (int i = 0; i < 4; ++i) {
        int m = bm + ty * 4 + i;
#pragma unroll
        for (int j = 0; j < 4; ++j) {
            int n = bn + tx * 4 + j;
            float v = acc[i][j];
            if (bias) v += bias[n];
            C[(size_t)m * N + n] = v;
        }
    }
}

// ---------------------------------------------------------------------------
// K1: partial polar bins per (b,h,k-chunk,x-chunk). Deterministic ws writes.
// Block 256 = 8 ki x 32 xt; x-range = [xc*XCH_, +XCH_).
// ---------------------------------------------------------------------------
__global__ __launch_bounds__(256) void bins_part(const float* __restrict__ qkv_k,
                                                 const float* __restrict__ qkv_x,
                                                 const int* __restrict__ polar_pos,
                                                 float* __restrict__ binspart) {
    const int b = blockIdx.z, h = blockIdx.y;
    const int kch = blockIdx.x / NS_, xc = blockIdx.x % NS_;
    const int k0 = kch * KC_;
    const int tid = threadIdx.x;
    const int ki = tid >> 5, xt = tid & 31;

    __shared__ __align__(16) float4 xs[XT_][9];
    __shared__ __align__(16) float kq_s[KC_][32];
    __shared__ int pol_s[KC_][68];

    if (tid < KC_ * 8) {
        int kk = tid >> 3, c = tid & 7;
        *(float4*)&kq_s[kk][c * 4] =
            *(const float4*)&qkv_k[(size_t)(b * KL_ + k0 + kk) * TDIM_ + h * HD_ + c * 4];
    }
    __syncthreads();
    float4 kqr[8];
#pragma unroll
    for (int c = 0; c < 8; ++c) kqr[c] = *(const float4*)&kq_s[ki][c * 4];

    const size_t xbase = (size_t)b * XL_;
    const int xbeg = xc * XCH_;
    float bins[PB_] = {};
    for (int t = 0; t < XCH_ / XT_; ++t) {
        const int x0 = xbeg + t * XT_;
        __syncthreads();
#pragma unroll
        for (int i = 0; i < 2; ++i) {
            int id = tid + 256 * i;
            int row = id >> 3, c = id & 7;
            xs[row][c] = *(const float4*)&qkv_x[(xbase + x0 + row) * TDIM_ + DIM_ + h * HD_ + c * 4];
        }
        if (tid < 128) {
            int kk = tid >> 4, c = tid & 15;
            *(int4*)&pol_s[kk][c * 4] =
                *(const int4*)&polar_pos[(size_t)(b * KL_ + k0 + kk) * XL_ + x0 + c * 4];
        }
        __syncthreads();
#pragma unroll
        for (int j = 0; j < 2; ++j) {
            int x = xt + 32 * j;
            float s = 0.f;
#pragma unroll
            for (int c = 0; c < 8; ++c) {
                float4 kv = xs[x][c];
                s += kqr[c].x * kv.x + kqr[c].y * kv.y + kqr[c].z * kv.z + kqr[c].w * kv.w;
            }
            float a = fabsf(s * SCALE_);
            int o = pol_s[ki][x];
#pragma unroll
            for (int q = 0; q < PB_; ++q) bins[q] += (o == q) ? a : 0.0f;
        }
    }
#pragma unroll
    for (int q = 0; q < PB_; ++q)
#pragma unroll
        for (int m = 1; m < 32; m <<= 1) bins[q] += __shfl_xor(bins[q], m, 32);
    if (xt == 0) {
        int row = (b * H_ + h) * KL_ + k0 + ki;
        float* dst = &binspart[(size_t)row * (NS_ * PB_) + xc * PB_];
#pragma unroll
        for (int q = 0; q < PB_; ++q) dst[q] = bins[q];
    }
}

// K2: reduce partials, argmax -> main_ori. One thread per (b,h,k) row.
__global__ __launch_bounds__(256) void bins_argmax(const float* __restrict__ binspart,
                                                   int* __restrict__ main_ori) {
    int row = blockIdx.x * 256 + threadIdx.x;
    if (row >= B_ * H_ * KL_) return;
    float s[PB_] = {};
    const float* bp = &binspart[(size_t)row * (NS_ * PB_)];
#pragma unroll
    for (int c = 0; c < NS_; ++c)
#pragma unroll
        for (int q = 0; q < PB_; ++q) s[q] += bp[c * PB_ + q];
    float best = s[0];
    int bi = 0;
#pragma unroll
    for (int q = 1; q < PB_; ++q)
        if (s[q] > best) { best = s[q]; bi = q; }
    main_ori[row] = bi;
}

// ---------------------------------------------------------------------------
// K3: flash partial per x-chunk: online softmax + AV over [xc*XCH_, +XCH_).
// Writes (acc[32], m, l) raw partials.
// ---------------------------------------------------------------------------
__global__ __launch_bounds__(256) void flash_part(const float* __restrict__ qkv_k,
                                                  const float* __restrict__ qkv_x,
                                                  const int* __restrict__ rd,
                                                  const int* __restrict__ polar_pos,
                                                  const int* __restrict__ att_mask,
                                                  const float* __restrict__ dis_embed,
                                                  const float* __restrict__ polar_emb,
                                                  const int* __restrict__ main_ori,
                                                  float* __restrict__ part) {
    const int b = blockIdx.z, h = blockIdx.y;
    const int kch = blockIdx.x / NS_, xc = blockIdx.x % NS_;
    const int k0 = kch * KC_;
    const int tid = threadIdx.x;
    const int ki = tid >> 5, xt = tid & 31;

    __shared__ __align__(16) float4 xs[XT_][9];
    __shared__ __align__(16) float4 vs[XT_][9];
    __shared__ __align__(16) float kq_s[KC_][32];
    __shared__ int pol_s[KC_][68];
    __shared__ int rd_s[KC_][68];
    __shared__ int msk_s[KC_][65];
    __shared__ float de[NDIS_ * H_];
    __shared__ float pe[PB_];

    for (int i = tid; i < NDIS_ * H_; i += 256) de[i] = dis_embed[i];
    if (tid < PB_) pe[tid] = polar_emb[tid];
    if (tid < KC_ * 8) {
        int kk = tid >> 3, c = tid & 7;
        *(float4*)&kq_s[kk][c * 4] =
            *(const float4*)&qkv_k[(size_t)(b * KL_ + k0 + kk) * TDIM_ + h * HD_ + c * 4];
    }
    __syncthreads();
    float4 kqr[8];
#pragma unroll
    for (int c = 0; c < 8; ++c) kqr[c] = *(const float4*)&kq_s[ki][c * 4];
    const int mo = main_ori[(b * H_ + h) * KL_ + k0 + ki];

    const size_t xbase = (size_t)b * XL_;
    const size_t mrow_base = (size_t)(b * H_ + h) * XL_;
    const int xbeg = xc * XCH_;

    float m_run = -3e38f, l_run = 0.f;
    float4 acc[8] = {};
    for (int t = 0; t < XCH_ / XT_; ++t) {
        const int x0 = xbeg + t * XT_;
        __syncthreads();
#pragma unroll
        for (int i = 0; i < 2; ++i) {
            int id = tid + 256 * i;
            int row = id >> 3, c = id & 7;
            size_t rb = (xbase + x0 + row) * TDIM_ + h * HD_ + c * 4;
            xs[row][c] = *(const float4*)&qkv_x[rb + DIM_];
            vs[row][c] = *(const float4*)&qkv_x[rb + 2 * DIM_];
        }
        if (tid < 128) {
            int kk = tid >> 4, c = tid & 15;
            size_t rb = (size_t)(b * KL_ + k0 + kk) * XL_ + x0 + c * 4;
            *(int4*)&pol_s[kk][c * 4] = *(const int4*)&polar_pos[rb];
            *(int4*)&rd_s[kk][c * 4] = *(const int4*)&rd[rb];
        } else {
            int id = tid - 128;
            int row = id >> 1, half = id & 1;
            int4 m4 = *(const int4*)&att_mask[(mrow_base + x0 + row) * KL_ + k0 + half * 4];
            msk_s[half * 4 + 0][row] = m4.x;
            msk_s[half * 4 + 1][row] = m4.y;
            msk_s[half * 4 + 2][row] = m4.z;
            msk_s[half * 4 + 3][row] = m4.w;
        }
        __syncthreads();
#pragma unroll
        for (int j = 0; j < 2; ++j) {
            int x = xt + 32 * j;
            float s = 0.f;
#pragma unroll
            for (int c = 0; c < 8; ++c) {
                float4 kv = xs[x][c];
                s += kqr[c].x * kv.x + kqr[c].y * kv.y + kqr[c].z * kv.z + kqr[c].w * kv.w;
            }
            s *= SCALE_;
            int r = rd_s[ki][x];
            int pp = pol_s[ki][x];
            int npb = pp - mo;
            npb += (npb >> 31) & PB_;
            float tval = (msk_s[ki][x] ? -1e6f : s) + de[r * H_ + h] + pe[npb];
            if (tval > m_run) {
                float alpha = expf(m_run - tval);
                l_run = l_run * alpha + 1.0f;
#pragma unroll
                for (int c = 0; c < 8; ++c) {
                    float4 vv = vs[x][c];
                    acc[c].x = acc[c].x * alpha + vv.x;
                    acc[c].y = acc[c].y * alpha + vv.y;
                    acc[c].z = acc[c].z * alpha + vv.z;
                    acc[c].w = acc[c].w * alpha + vv.w;
                }
                m_run = tval;
            } else {
                float p = expf(tval - m_run);
                l_run += p;
#pragma unroll
                for (int c = 0; c < 8; ++c) {
                    float4 vv = vs[x][c];
                    acc[c].x += p * vv.x;
                    acc[c].y += p * vv.y;
                    acc[c].z += p * vv.z;
                    acc[c].w += p * vv.w;
                }
            }
        }
    }
    // merge 32 lanes
    float M = m_run;
#pragma unroll
    for (int m = 1; m < 32; m <<= 1) M = fmaxf(M, __shfl_xor(M, m, 32));
    float factor = expf(m_run - M);
    l_run *= factor;
#pragma unroll
    for (int c = 0; c < 8; ++c) {
        acc[c].x *= factor; acc[c].y *= factor; acc[c].z *= factor; acc[c].w *= factor;
    }
#pragma unroll
    for (int m = 1; m < 32; m <<= 1) {
        l_run += __shfl_xor(l_run, m, 32);
#pragma unroll
        for (int c = 0; c < 8; ++c) {
            acc[c].x += __shfl_xor(acc[c].x, m, 32);
            acc[c].y += __shfl_xor(acc[c].y, m, 32);
            acc[c].z += __shfl_xor(acc[c].z, m, 32);
            acc[c].w += __shfl_xor(acc[c].w, m, 32);
        }
    }
    if (xt == 0) {
        int row = (b * H_ + h) * KL_ + k0 + ki;
        float* dst = &part[(size_t)(row * NS_ + xc) * 36];
#pragma unroll
        for (int c = 0; c < 8; ++c) *(float4*)&dst[c * 4] = acc[c];
        dst[32] = M;
        dst[33] = l_run;
    }
}

// K4: merge NS_ partials per row -> kout_pre. Block 256 = 8 rows x 32 d.
__global__ __launch_bounds__(256) void flash_merge(const float* __restrict__ part,
                                                   float* __restrict__ kout_pre) {
    const int tid = threadIdx.x;
    const int ri = tid >> 5, d = tid & 31;
    const int row = blockIdx.x * 8 + ri;
    float mc[NS_], lc[NS_];
    float M = -3e38f;
#pragma unroll
    for (int c = 0; c < NS_; ++c) {
        const float* p = &part[(size_t)(row * NS_ + c) * 36];
        mc[c] = p[32];
        lc[c] = p[33];
        M = fmaxf(M, mc[c]);
    }
    float l = 0.f, a = 0.f;
#pragma unroll
    for (int c = 0; c < NS_; ++c) {
        float w = expf(mc[c] - M);
        l += lc[c] * w;
        a += part[(size_t)(row * NS_ + c) * 36 + d] * w;
    }
    int k = row & (KL_ - 1);
    int bh = row >> 7;           // row / KL_
    int h = bh & (H_ - 1), b = bh >> 3;
    kout_pre[(size_t)(b * KL_ + k) * DIM_ + h * HD_ + d] = a / l;
}

// ---------------------------------------------------------------------------
// x-direction attention (unchanged)
// ---------------------------------------------------------------------------
__global__ __launch_bounds__(256) void attn_x(const float* __restrict__ qkv_x,
                                              const float* __restrict__ qkv_k,
                                              const int* __restrict__ rd,
                                              const int* __restrict__ polar_pos,
                                              const int* __restrict__ att_mask,
                                              const float* __restrict__ dis_embed,
                                              const float* __restrict__ polar_emb,
                                              const int* __restrict__ main_ori,
                                              float* __restrict__ xout_pre) {
    const int b = blockIdx.z, h = blockIdx.y;
    const int x0 = blockIdx.x * 16;
    const int tid = threadIdx.x;
    __shared__ __align__(16) float kk_s[KL_][36];
    __shared__ __align__(16) float kv_s[KL_][36];
    __shared__ __align__(16) float q_s[16][36];
    __shared__ float de[NDIS_ * H_];
    __shared__ float pe[PB_];
    __shared__ int mo_s[KL_];

    for (int i = tid; i < KL_ * HD_; i += 256) {
        int kk = i >> 5, d = i & 31;
        size_t base = (size_t)(b * KL_ + kk) * TDIM_ + h * HD_ + d;
        kk_s[kk][d] = qkv_k[base + DIM_];
        kv_s[kk][d] = qkv_k[base + 2 * DIM_];
    }
    for (int i = tid; i < 16 * HD_; i += 256) {
        int xl = i >> 5, d = i & 31;
        q_s[xl][d] = qkv_x[(size_t)(b * XL_ + x0 + xl) * TDIM_ + h * HD_ + d];
    }
    for (int i = tid; i < NDIS_ * H_; i += 256) de[i] = dis_embed[i];
    if (tid < PB_) pe[tid] = polar_emb[tid];
    if (tid < KL_) mo_s[tid] = main_ori[(b * H_ + h) * KL_ + tid];
    __syncthreads();

    const int xl = tid >> 4, r = tid & 15;
    const int x = x0 + xl;
    float t[8];
    float lmax = -3e38f;
    const size_t mrow = ((size_t)(b * H_ + h) * XL_ + x) * KL_;
#pragma unroll
    for (int j = 0; j < 8; ++j) {
        int kk = j * 16 + r;
        float s = 0.f;
#pragma unroll
        for (int d4 = 0; d4 < 8; ++d4) {
            float4 a = *(const float4*)&q_s[xl][d4 * 4];
            float4 bb = *(const float4*)&kk_s[kk][d4 * 4];
            s += a.x * bb.x + a.y * bb.y + a.z * bb.z + a.w * bb.w;
        }
        s *= SCALE_;
        int msk = att_mask[mrow + kk];
        size_t pidx = (size_t)(b * KL_ + kk) * XL_ + x;
        int rv = rd[pidx];
        int pp = polar_pos[pidx];
        int npb = pp - mo_s[kk];
        npb += (npb >> 31) & PB_;
        t[j] = (msk ? -1e9f : s) + de[rv * H_ + h] + pe[npb];
        lmax = fmaxf(lmax, t[j]);
    }
#pragma unroll
    for (int m = 1; m < 16; m <<= 1) lmax = fmaxf(lmax, __shfl_xor(lmax, m, 16));
    float lsum = 0.f;
#pragma unroll
    for (int j = 0; j < 8; ++j) {
        t[j] = expf(t[j] - lmax);
        lsum += t[j];
    }
#pragma unroll
    for (int m = 1; m < 16; m <<= 1) lsum += __shfl_xor(lsum, m, 16);

    float acc[HD_] = {};
#pragma unroll
    for (int j = 0; j < 8; ++j) {
        int kk = j * 16 + r;
        float e = t[j];
#pragma unroll
        for (int d = 0; d < HD_; d += 4) {
            float4 vv = *(const float4*)&kv_s[kk][d];
            acc[d + 0] += e * vv.x;
            acc[d + 1] += e * vv.y;
            acc[d + 2] += e * vv.z;
            acc[d + 3] += e * vv.w;
        }
    }
#pragma unroll
    for (int d = 0; d < HD_; ++d)
#pragma unroll
        for (int m = 1; m < 16; m <<= 1) acc[d] += __shfl_xor(acc[d], m, 16);
    if (r == 0) {
        float inv = 1.0f / lsum;
        float* op = xout_pre + (size_t)(b * XL_ + x) * DIM_ + h * HD_;
#pragma unroll
        for (int d = 0; d < HD_; ++d) op[d] = acc[d] * inv;
    }
}

// ---------------------------------------------------------------------------
extern "C" void kernel_launch(void* const* d_in, const int* in_sizes, int n_in,
                              void* d_out, int out_size, void* d_ws, size_t ws_size,
                              hipStream_t stream) {
    const float* x         = (const float*)d_in[0];
    const float* kernal    = (const float*)d_in[1];
    const int* rd          = (const int*)d_in[2];
    const int* polar_pos   = (const int*)d_in[3];
    const int* att_mask    = (const int*)d_in[4];
    const float* W_qkv     = (const float*)d_in[5];
    const float* dis_embed = (const float*)d_in[6];
    const float* polar_emb = (const float*)d_in[7];
    const float* W_proj    = (const float*)d_in[8];
    const float* b_proj    = (const float*)d_in[9];
    float* out             = (float*)d_out;

    char* base = (char*)d_ws;
    size_t off = 0;
    auto alloc = [&](size_t bytes) { void* p = base + off; off = (off + bytes + 255) & ~255ULL; return p; };
    float* qkv_x    = (float*)alloc((size_t)B_ * XL_ * TDIM_ * 4);   // 50.3 MB
    float* qkv_k    = (float*)alloc((size_t)B_ * KL_ * TDIM_ * 4);   // 1.6 MB
    float* xout_pre = (float*)alloc((size_t)B_ * XL_ * DIM_ * 4);    // 16.8 MB
    float* kout_pre = (float*)alloc((size_t)B_ * KL_ * DIM_ * 4);    // 0.5 MB
    int* main_ori   = (int*)alloc(B_ * H_ * KL_ * 4);
    // part/binspart alias xout_pre (dead until attn_x, which runs after merge)
    float* part     = xout_pre;                                       // 4096*NS_*36 floats = 2.4 MB
    float* binspart = xout_pre + 4096 * NS_ * 36 + 256;               // 4096*NS_*8 floats = 0.5 MB

    gemm128<<<dim3(TDIM_ / 128, (B_ * XL_) / 128), 256, 0, stream>>>(
        x, W_qkv, qkv_x, nullptr, B_ * XL_, TDIM_, DIM_);
    gemm64<<<dim3(TDIM_ / 64, (B_ * KL_) / 64), 256, 0, stream>>>(
        kernal, W_qkv, qkv_k, nullptr, B_ * KL_, TDIM_, DIM_);
    bins_part<<<dim3((KL_ / KC_) * NS_, H_, B_), 256, 0, stream>>>(
        qkv_k, qkv_x, polar_pos, binspart);
    bins_argmax<<<dim3((B_ * H_ * KL_ + 255) / 256), 256, 0, stream>>>(binspart, main_ori);
    flash_part<<<dim3((KL_ / KC_) * NS_, H_, B_), 256, 0, stream>>>(
        qkv_k, qkv_x, rd, polar_pos, att_mask, dis_embed, polar_emb, main_ori, part);
    flash_merge<<<dim3(B_ * H_ * KL_ / 8), 256, 0, stream>>>(part, kout_pre);
    attn_x<<<dim3(XL_ / 16, H_, B_), 256, 0, stream>>>(
        qkv_x, qkv_k, rd, polar_pos, att_mask, dis_embed, polar_emb, main_ori, xout_pre);
    gemm128<<<dim3(DIM_ / 128, (B_ * XL_) / 128), 256, 0, stream>>>(
        xout_pre, W_proj, out, b_proj, B_ * XL_, DIM_, DIM_);
    gemm64<<<dim3(DIM_ / 64, (B_ * KL_) / 64), 256, 0, stream>>>(
        kout_pre, W_proj, out + (size_t)B_ * XL_ * DIM_, b_proj, B_ * KL_, DIM_, DIM_);
}